// Round 1
// baseline (317.889 us; speedup 1.0000x reference)
//
#include <hip/hip_runtime.h>
#include <math.h>

#define NN 8192
#define PP 32
#define HH 512
#define KK 100
#define DD 64
#define RR 32
#define MM 96      // GEMM output rows: 32 gate + 64 w
#define CH 128     // scan chunk length
#define GG 64      // number of chunks (GG*CH == NN)

// workspace layout (float offsets)
#define OFF_VINV   0                      // 64*64
#define OFF_M      (OFF_VINV + DD*DD)     // 96*512 packed [gate_w; Vinv@B]
#define OFF_EAT    (OFF_M + MM*HH)        // 100*64  (E@alpha)^T
#define OFF_RHT    (OFF_EAT + KK*DD)      // 100*64  (Vinv@E@alpha)^T
#define OFF_Y0     (OFF_RHT + KK*DD)      // 64      Vinv@x0
#define OFF_C      (OFF_Y0 + DD)          // 8192*96 gemm out
#define OFF_COEF   (OFF_C + NN*MM)        // 8192*32*4 (a,c,br,bi)
#define OFF_AGG    (OFF_COEF + NN*PP*4)   // 64*32*4 chunk aggregates
#define OFF_YST    (OFF_AGG + GG*PP*4)    // 64*32*2 chunk-start y
#define OFF_Y      (OFF_YST + GG*PP*2)    // 8192*64 y_right

__device__ __forceinline__ float softplusf(float x) {
    return x > 20.f ? x : log1pf(expf(x));
}

// ---------------------------------------------------------------------------
// kA: Gauss-Jordan inverse of V (64x64, diag-dominant, no pivoting), pack
//     gate_w into M rows 0..31, compute y0 = Vinv @ x0.
__global__ __launch_bounds__(256) void kA(const float* __restrict__ V,
                                          const float* __restrict__ gate_w,
                                          const float* __restrict__ x0,
                                          float* __restrict__ ws) {
    __shared__ float aug[DD][130];
    __shared__ float prow[2 * DD];
    int t = threadIdx.x;
    for (int idx = t; idx < DD * DD; idx += 256) {
        int i = idx >> 6, j = idx & 63;
        aug[i][j] = V[idx];
        aug[i][64 + j] = (i == j) ? 1.f : 0.f;
    }
    __syncthreads();
    int row = t >> 2, cs = (t & 3) * 32;
    for (int k = 0; k < DD; k++) {
        float invp = 1.f / aug[k][k];
        float f = aug[row][k];
        if (t < 128) prow[t] = aug[k][t] * invp;
        __syncthreads();
        if (row == k) {
            for (int j = 0; j < 32; j++) aug[row][cs + j] = prow[cs + j];
        } else {
            for (int j = 0; j < 32; j++) aug[row][cs + j] -= f * prow[cs + j];
        }
        __syncthreads();
    }
    for (int idx = t; idx < DD * DD; idx += 256) {
        int i = idx >> 6, j = idx & 63;
        ws[OFF_VINV + idx] = aug[i][64 + j];
    }
    const float4* gw4 = (const float4*)gate_w;
    float4* m4 = (float4*)(ws + OFF_M);
    for (int idx = t; idx < PP * HH / 4; idx += 256) m4[idx] = gw4[idx];
    if (t < DD) {
        float s = 0.f;
        for (int j = 0; j < DD; j++) s += aug[t][64 + j] * x0[j];
        ws[OFF_Y0 + t] = s;
    }
}

// ---------------------------------------------------------------------------
// kA2: blocks 0..31: M rows 32..95 = Vinv @ B  (64x512)
//      blocks 32..56: EA_t[k][d] = (E@alpha)[d][k], rhat_t[k][d] = (Vinv@EA)[d][k]
__global__ __launch_bounds__(256) void kA2(const float* __restrict__ B,
                                           const float* __restrict__ E,
                                           const float* __restrict__ alpha,
                                           float* __restrict__ ws) {
    int b = blockIdx.x, t = threadIdx.x;
    const float* Vinv = ws + OFF_VINV;
    if (b < 32) {
        int d = b * 2 + (t >> 7);
        int h0 = (t & 127) * 4;
        float4 acc = {0.f, 0.f, 0.f, 0.f};
        for (int j = 0; j < DD; j++) {
            float v = Vinv[d * DD + j];
            float4 b4 = *(const float4*)&B[j * HH + h0];
            acc.x += v * b4.x; acc.y += v * b4.y;
            acc.z += v * b4.z; acc.w += v * b4.w;
        }
        *(float4*)&ws[OFF_M + (32 + d) * HH + h0] = acc;
    } else {
        int k = (b - 32) * 4 + (t >> 6);
        int d = t & 63;
        float ea = 0.f;
        #pragma unroll
        for (int r = 0; r < RR; r++) ea += E[d * RR + r] * alpha[r * KK + k];
        ws[OFF_EAT + k * DD + d] = ea;
        float rr = 0.f;
        #pragma unroll
        for (int j = 0; j < DD; j++) rr += Vinv[d * DD + j] * __shfl(ea, j, 64);
        ws[OFF_RHT + k * DD + d] = rr;
    }
}

// ---------------------------------------------------------------------------
// kB: C[n][m] = sum_k u[n][k] * M[m][k]   (8192x512 @ 512x96)
//     BN=32 rows/block, BK=64, 128 threads, per-thread 4n x 6m, XOR-swizzled LDS
__global__ __launch_bounds__(128) void kB(const float* __restrict__ u,
                                          float* __restrict__ ws) {
    __shared__ float uT[32 * 64];
    __shared__ float mT[96 * 64];
    int t = threadIdx.x;
    int n0 = blockIdx.x * 32;
    int tn = t & 7, tm = t >> 3;
    const float* Mg = ws + OFF_M;
    float acc[4][6];
    #pragma unroll
    for (int i = 0; i < 4; i++)
        #pragma unroll
        for (int j = 0; j < 6; j++) acc[i][j] = 0.f;

    for (int kc = 0; kc < HH; kc += 64) {
        #pragma unroll
        for (int s = 0; s < 4; s++) {
            int idx = t + 128 * s;
            int r = idx >> 4, c4 = idx & 15;
            float4 f4 = *(const float4*)&u[(n0 + r) * HH + kc + c4 * 4];
            *(float4*)&uT[r * 64 + ((c4 ^ ((r >> 2) & 7)) << 2)] = f4;
        }
        #pragma unroll
        for (int s = 0; s < 12; s++) {
            int idx = t + 128 * s;
            int r = idx >> 4, c4 = idx & 15;
            float4 f4 = *(const float4*)&Mg[r * HH + kc + c4 * 4];
            *(float4*)&mT[r * 64 + ((c4 ^ (r & 7)) << 2)] = f4;
        }
        __syncthreads();
        #pragma unroll
        for (int k4 = 0; k4 < 16; k4++) {
            float4 uu[4], mm[6];
            #pragma unroll
            for (int i = 0; i < 4; i++)
                uu[i] = *(float4*)&uT[(4 * tn + i) * 64 + ((k4 ^ (tn & 7)) << 2)];
            #pragma unroll
            for (int j = 0; j < 6; j++) {
                int m = 6 * tm + j;
                mm[j] = *(float4*)&mT[m * 64 + ((k4 ^ (m & 7)) << 2)];
            }
            #pragma unroll
            for (int i = 0; i < 4; i++)
                #pragma unroll
                for (int j = 0; j < 6; j++)
                    acc[i][j] += uu[i].x * mm[j].x + uu[i].y * mm[j].y +
                                 uu[i].z * mm[j].z + uu[i].w * mm[j].w;
        }
        __syncthreads();
    }
    #pragma unroll
    for (int i = 0; i < 4; i++)
        #pragma unroll
        for (int j = 0; j < 6; j++)
            ws[OFF_C + (n0 + 4 * tn + i) * MM + 6 * tm + j] = acc[i][j];
}

// ---------------------------------------------------------------------------
// kC1: per (n,p) step coefficients: z=(a,c), b = gated(q*w) + rhat[mark]
__global__ __launch_bounds__(256) void kC1(const float* __restrict__ times,
                                           const int* __restrict__ marks,
                                           const float* __restrict__ llr_,
                                           const float* __restrict__ lim_,
                                           const float* __restrict__ gate_b,
                                           float* __restrict__ ws) {
    int gid = blockIdx.x * 256 + threadIdx.x;
    int n = gid >> 5, p = gid & 31;
    float tcur = times[n];
    float dtv = (n == 0) ? tcur : tcur - times[n - 1];
    float gp = ws[OFF_C + n * MM + p] + gate_b[p];
    float gate = softplusf(gp);
    float real = -softplusf(llr_[p]) * gate;
    float imag = lim_[p];
    float e = expf(real * dtv);
    float cb = cosf(imag * dtv), sb = sinf(imag * dtv);
    float a = e * cb, c = e * sb;
    float denom = real * real + imag * imag;
    float dn = denom + 1e-12f;
    float nre = a - 1.f, nim = c;
    float qr = (nre * real + nim * imag) / dn;
    float qi = (nim * real - nre * imag) / dn;
    if (denom < 1e-8f) { qr = dtv; qi = 0.f; }
    float2 w = *(const float2*)&ws[OFF_C + n * MM + 32 + 2 * p];
    float br = qr * w.x - qi * w.y;
    float bi = qr * w.y + qi * w.x;
    if (!(dtv > 0.f)) { br = 0.f; bi = 0.f; }
    int mk = marks[n];
    br += ws[OFF_RHT + mk * DD + 2 * p];
    bi += ws[OFF_RHT + mk * DD + 2 * p + 1];
    *(float4*)&ws[OFF_COEF + (n * PP + p) * 4] = make_float4(a, c, br, bi);
}

// ---------------------------------------------------------------------------
// kC2a: per (chunk g, pole p): compose 128 steps into (z, b)
__global__ __launch_bounds__(256) void kC2a(float* __restrict__ ws) {
    int gid = blockIdx.x * 256 + threadIdx.x;
    int g = gid >> 5, p = gid & 31;
    float zr = 1.f, zi = 0.f, br = 0.f, bi = 0.f;
    const float4* cf = (const float4*)(ws + OFF_COEF);
    int base = g * CH * PP + p;
    #pragma unroll 4
    for (int i = 0; i < CH; i++) {
        float4 cc = cf[base + i * PP];
        float nzr = cc.x * zr - cc.y * zi;
        float nzi = cc.x * zi + cc.y * zr;
        float nbr = cc.x * br - cc.y * bi + cc.z;
        float nbi = cc.x * bi + cc.y * br + cc.w;
        zr = nzr; zi = nzi; br = nbr; bi = nbi;
    }
    *(float4*)&ws[OFF_AGG + (g * PP + p) * 4] = make_float4(zr, zi, br, bi);
}

// kC2b: sequential scan over 64 chunk aggregates -> chunk-start y
__global__ __launch_bounds__(64) void kC2b(float* __restrict__ ws) {
    int t = threadIdx.x;
    if (t >= PP) return;
    float yr = ws[OFF_Y0 + 2 * t], yi = ws[OFF_Y0 + 2 * t + 1];
    #pragma unroll 8
    for (int g = 0; g < GG; g++) {
        *(float2*)&ws[OFF_YST + (g * PP + t) * 2] = make_float2(yr, yi);
        float4 ag = *(const float4*)&ws[OFF_AGG + (g * PP + t) * 4];
        float nyr = ag.x * yr - ag.y * yi + ag.z;
        float nyi = ag.x * yi + ag.y * yr + ag.w;
        yr = nyr; yi = nyi;
    }
}

// kC2c: re-run each chunk from known start, emit y_right[n]
__global__ __launch_bounds__(256) void kC2c(float* __restrict__ ws) {
    int gid = blockIdx.x * 256 + threadIdx.x;
    int g = gid >> 5, p = gid & 31;
    float2 y = *(const float2*)&ws[OFF_YST + (g * PP + p) * 2];
    const float4* cf = (const float4*)(ws + OFF_COEF);
    int base = g * CH * PP + p;
    #pragma unroll 4
    for (int i = 0; i < CH; i++) {
        float4 cc = cf[base + i * PP];
        float nyr = cc.x * y.x - cc.y * y.y + cc.z;
        float nyi = cc.x * y.y + cc.y * y.x + cc.w;
        y.x = nyr; y.y = nyi;
        *(float2*)&ws[OFF_Y + (g * CH + i) * DD + 2 * p] = y;
    }
}

// ---------------------------------------------------------------------------
// kD: x_right[n] = V @ y[n]; x_left = x_right - (E@alpha)[:,mark]
//     one wave per 8 timesteps; V row in registers; y broadcast via shfl
__global__ __launch_bounds__(256) void kD(const float* __restrict__ V,
                                          const int* __restrict__ marks,
                                          const float* __restrict__ ws,
                                          float* __restrict__ out) {
    int t = threadIdx.x;
    int lane = t & 63;
    int nb = blockIdx.x * 32 + (t >> 6) * 8;
    float vrow[DD];
    #pragma unroll
    for (int c = 0; c < 16; c++) {
        float4 v4 = *(const float4*)&V[lane * DD + c * 4];
        vrow[c * 4 + 0] = v4.x; vrow[c * 4 + 1] = v4.y;
        vrow[c * 4 + 2] = v4.z; vrow[c * 4 + 3] = v4.w;
    }
    for (int q = 0; q < 8; q++) {
        int n = nb + q;
        float yv = ws[OFF_Y + n * DD + lane];
        float acc = 0.f;
        #pragma unroll
        for (int j = 0; j < DD; j++) acc += vrow[j] * __shfl(yv, j, 64);
        int mk = marks[n];
        float r = ws[OFF_EAT + mk * DD + lane];
        out[n * DD + lane] = acc;
        out[NN * DD + n * DD + lane] = acc - r;
    }
}

// ---------------------------------------------------------------------------
extern "C" void kernel_launch(void* const* d_in, const int* in_sizes, int n_in,
                              void* d_out, int out_size, void* d_ws, size_t ws_size,
                              hipStream_t stream) {
    (void)in_sizes; (void)n_in; (void)out_size; (void)ws_size;
    const float* times  = (const float*)d_in[0];
    const int*   marks  = (const int*)d_in[1];
    const float* u      = (const float*)d_in[2];
    const float* llr    = (const float*)d_in[3];
    const float* lim    = (const float*)d_in[4];
    const float* V      = (const float*)d_in[5];
    const float* B      = (const float*)d_in[6];
    const float* E      = (const float*)d_in[7];
    const float* alpha  = (const float*)d_in[8];
    const float* gate_w = (const float*)d_in[9];
    const float* gate_b = (const float*)d_in[10];
    const float* x0     = (const float*)d_in[11];
    float* ws  = (float*)d_ws;
    float* out = (float*)d_out;

    hipLaunchKernelGGL(kA,   dim3(1),    dim3(256), 0, stream, V, gate_w, x0, ws);
    hipLaunchKernelGGL(kA2,  dim3(57),   dim3(256), 0, stream, B, E, alpha, ws);
    hipLaunchKernelGGL(kB,   dim3(256),  dim3(128), 0, stream, u, ws);
    hipLaunchKernelGGL(kC1,  dim3(1024), dim3(256), 0, stream, times, marks, llr, lim, gate_b, ws);
    hipLaunchKernelGGL(kC2a, dim3(8),    dim3(256), 0, stream, ws);
    hipLaunchKernelGGL(kC2b, dim3(1),    dim3(64),  0, stream, ws);
    hipLaunchKernelGGL(kC2c, dim3(8),    dim3(256), 0, stream, ws);
    hipLaunchKernelGGL(kD,   dim3(256),  dim3(256), 0, stream, V, marks, ws, out);
}